// Round 2
// 158.340 us; speedup vs baseline: 1.0457x; 1.0457x over previous
//
#include <hip/hip_runtime.h>
#include <hip/hip_bf16.h>

typedef __hip_bfloat16 bf16;
typedef __attribute__((ext_vector_type(8))) short short8;   // 8 bf16 = K=32 MFMA A/B frag
typedef __attribute__((ext_vector_type(4))) short short4v;  // 4 bf16 = K=16 MFMA A/B frag
typedef __attribute__((ext_vector_type(4))) float f32x4;    // MFMA C/D frag
typedef __attribute__((ext_vector_type(4))) unsigned uint4v;

#define NB 128   // B*TO
#define CC 64    // channels
#define TT 1024  // time

#if __has_builtin(__builtin_amdgcn_exp2f)
#define EXP2(x) __builtin_amdgcn_exp2f(x)
#else
#define EXP2(x) exp2f(x)
#endif

// ---- cheap bf16 conversion: round-half-up via +0x8000, pack 2 per v_perm ---
__device__ __forceinline__ unsigned rnd_u(float f) {
  return __builtin_bit_cast(unsigned, f) + 0x8000u;
}
__device__ __forceinline__ short f2bfs_fast(float f) {
  return (short)(rnd_u(f) >> 16);
}
__device__ __forceinline__ unsigned packbf2(unsigned uhi, unsigned ulo) {
  return __builtin_amdgcn_perm(uhi, ulo, 0x07060302);
}
__device__ __forceinline__ short4v pack4(float a, float b, float c, float d) {
  unsigned pd[2] = { packbf2(rnd_u(b), rnd_u(a)), packbf2(rnd_u(d), rnd_u(c)) };
  return *(const short4v*)pd;
}

__device__ __forceinline__ f32x4 mfma32(short8 a, short8 b, f32x4 c) {
  return __builtin_amdgcn_mfma_f32_16x16x32_bf16(a, b, c, 0, 0, 0);
}

// ---------------------------------------------------------------------------
// Kernel 0: weight convert fp32->bf16 (one-time). Wq PRE-SCALED by
// scale*log2(e) so scores feed exp2 directly.
// r13: Wo is stored PERMUTED so the attn epilogue's K=32 A-frag is one
// contiguous short8: position o*64 + u*32 + q4*8 + j holds
// Wo[o][(2u+(j>>2))*16 + q4*4 + (j&3)].
// ---------------------------------------------------------------------------
__global__ __launch_bounds__(256) void wcvt(
    const float* __restrict__ Wq, const float* __restrict__ Wk,
    const float* __restrict__ Wv, const float* __restrict__ Wo,
    const float* __restrict__ scale_p, bf16* __restrict__ wb)
{
  const int i = blockIdx.x * 256 + threadIdx.x;
  float f;
  if      (i <  4096) f = Wq[i] * (*scale_p) * 1.44269504089f;
  else if (i <  8192) f = Wk[i - 4096];
  else if (i < 12288) f = Wv[i - 8192];
  else {
    const int ii = i - 12288;
    const int o  = ii >> 6;
    const int cp = ii & 63;                       // permuted column position
    const int u  = cp >> 5, q4 = (cp >> 3) & 3, j = cp & 7;
    const int c  = (2 * u + (j >> 2)) * 16 + q4 * 4 + (j & 3);
    f = Wo[o * 64 + c];
  }
  wb[i] = __float2bfloat16(f);
}

// ---------------------------------------------------------------------------
// Kernel 1: MFMA q/k/v projections. qt/kt in [n][t][c].
// V is written in a PERMUTED [n][c][s'] layout: within each 64-s block,
// s = a*16+b*4+j is stored at s' = b*16+a*4+j. One b128 read from LDS then
// yields the K=32 PV A-frag for a strip PAIR (r13: consumed directly by
// mfma_16x16x32 instead of being split into two K=16 frags).
// ---------------------------------------------------------------------------
__global__ __launch_bounds__(256) void qkv_mfma(
    const float* __restrict__ x, const bf16* __restrict__ wb,
    bf16* __restrict__ qt, bf16* __restrict__ kt, bf16* __restrict__ v)
{
  __shared__ short xs[64 * 72];   // x^T tile [t][c]
  __shared__ short ys[64 * 72];   // output assembly buffer

  const int n  = blockIdx.y;
  const int t0 = blockIdx.x * 64;
  const int tid = threadIdx.x;
  const int w  = tid >> 6, il = tid & 15, q4 = (tid & 63) >> 4;
  const size_t nbase = (size_t)n * (CC * TT);

  {
    const int tc = tid & 15;
    const int c0 = (tid >> 4) * 4;
    float fe[4][4];
    #pragma unroll
    for (int j = 0; j < 4; j++) {
      float4 fj = *(const float4*)&x[nbase + (size_t)(c0 + j) * TT + t0 + tc * 4];
      fe[j][0] = fj.x; fe[j][1] = fj.y; fe[j][2] = fj.z; fe[j][3] = fj.w;
    }
    #pragma unroll
    for (int e = 0; e < 4; e++)
      *(short4v*)&xs[(tc * 4 + e) * 72 + c0] = pack4(fe[0][e], fe[1][e], fe[2][e], fe[3][e]);
  }
  __syncthreads();

  short8 xa[2];
  #pragma unroll
  for (int kk = 0; kk < 2; kk++)
    xa[kk] = *(const short8*)&xs[(w * 16 + il) * 72 + kk * 32 + q4 * 8];

  const bf16* wq = wb;
  const bf16* wk = wb + 4096;
  const bf16* wv = wb + 8192;

  f32x4 aq[4], ak[4], av[4];
  #pragma unroll
  for (int i = 0; i < 4; i++) {
    aq[i] = (f32x4){0.f,0.f,0.f,0.f};
    ak[i] = (f32x4){0.f,0.f,0.f,0.f};
    av[i] = (f32x4){0.f,0.f,0.f,0.f};
  }

  #pragma unroll
  for (int kk = 0; kk < 2; kk++) {
    #pragma unroll
    for (int ot = 0; ot < 4; ot++) {
      const int ridx = (ot * 16 + il) * 64 + kk * 32 + q4 * 8;
      short8 bq = *(const short8*)&wq[ridx];
      short8 bk = *(const short8*)&wk[ridx];
      short8 bv = *(const short8*)&wv[ridx];
      aq[ot] = mfma32(xa[kk], bq, aq[ot]);   // D[t][o]
      ak[ot] = mfma32(xa[kk], bk, ak[ot]);   // D[t][o]
      av[ot] = mfma32(bv, xa[kk], av[ot]);   // D[o][t]
    }
  }

  const int rr = tid >> 2;
  const int sg = (tid & 3) * 8;

  __syncthreads();
  #pragma unroll
  for (int ot = 0; ot < 4; ot++)
    #pragma unroll
    for (int r = 0; r < 4; r++)
      ys[(w * 16 + q4 * 4 + r) * 72 + ot * 16 + il] = f2bfs_fast(aq[ot][r]);
  __syncthreads();
  *(short8*)&qt[nbase + (size_t)(t0 + rr) * 64 + sg]      = *(const short8*)&ys[rr * 72 + sg];
  *(short8*)&qt[nbase + (size_t)(t0 + rr) * 64 + sg + 32] = *(const short8*)&ys[rr * 72 + sg + 32];

  __syncthreads();
  #pragma unroll
  for (int ot = 0; ot < 4; ot++)
    #pragma unroll
    for (int r = 0; r < 4; r++)
      ys[(w * 16 + q4 * 4 + r) * 72 + ot * 16 + il] = f2bfs_fast(ak[ot][r]);
  __syncthreads();
  *(short8*)&kt[nbase + (size_t)(t0 + rr) * 64 + sg]      = *(const short8*)&ys[rr * 72 + sg];
  *(short8*)&kt[nbase + (size_t)(t0 + rr) * 64 + sg + 32] = *(const short8*)&ys[rr * 72 + sg + 32];

  __syncthreads();
  // V with permuted s-column: t_local = w*16+il -> col (il>>2)*16 + w*4 + (il&3)
  #pragma unroll
  for (int ot = 0; ot < 4; ot++)
    #pragma unroll
    for (int r = 0; r < 4; r++)
      ys[(ot * 16 + q4 * 4 + r) * 72 + (il >> 2) * 16 + w * 4 + (il & 3)] =
          f2bfs_fast(av[ot][r]);
  __syncthreads();
  *(short8*)&v[nbase + (size_t)rr * TT + t0 + sg]      = *(const short8*)&ys[rr * 72 + sg];
  *(short8*)&v[nbase + (size_t)rr * TT + t0 + sg + 32] = *(const short8*)&ys[rr * 72 + sg + 32];
}

// ---------------------------------------------------------------------------
// Kernel 2: flash attention + Wo + residual. r11/r12 structure preserved
// ((256,4), 128-q blocks, grid 1024, reg-prefetch across barriers, coalesced
// fp32 epilogue, ones-MFMA denominator, no online max).
// r13 change: ALL remaining K=16 MFMAs upgraded to K=32 (928 -> 592 MFMAs,
// all full-rate). Validity: mfma sums over k in any order, so the K=32 B-frag
// for PV is just the register CONCATENATION of two adjacent K=16 P strips
// (both halves use k=q4*4+r within their strip), and the permuted-V b128 read
// h0/h1 already IS the matching K=32 A-frag. Same trick for the l-sum
// (ones8) and the Wo epilogue (Wo pre-permuted in wcvt).
// Layouts (m89/m120-verified): A[m=lane&15][k=quad*8+j];
// B[k=quad*8+j][n=lane&15]; C/D row=quad*4+reg, col=lane&15.
// ---------------------------------------------------------------------------
__global__ __launch_bounds__(256, 4) void attn_flash(
    const bf16* __restrict__ qt, const bf16* __restrict__ kt,
    const bf16* __restrict__ v,  const bf16* __restrict__ wob,
    const float* __restrict__ x, float* __restrict__ out)
{
  __shared__ float obuf[64 * 132];          // 33792 B; ks/vs alias the front
  short* ks = (short*)obuf;                 // K tile [s][c]     (9216 B)
  short* vs = ks + 64 * 72;                 // V tile [c][s']    (9216 B)

  const int bid = blockIdx.x;
  const int n   = bid & 127;        // bid%8 == n%8 -> same-n blocks share an XCD
  const int qt0 = (bid >> 7) * 128;
  const int tid = threadIdx.x;
  const int w   = tid >> 6;
  const int il  = tid & 15;
  const int q4  = (tid & 63) >> 4;
  const size_t nbase = (size_t)n * (CC * TT);

  // staging coords: 2 chunks of 16B each for K and V
  const int srow0 = tid >> 3, scol = (tid & 7) * 8;
  const int srow1 = srow0 + 32;

  // persistent Q B-frags (pre-scaled): B[k=c][n=t], wave's 32 queries
  short8 qb[2][2];
  #pragma unroll
  for (int mt = 0; mt < 2; mt++)
    #pragma unroll
    for (int kk = 0; kk < 2; kk++)
      qb[mt][kk] = *(const short8*)&qt[nbase +
          (size_t)(qt0 + w * 32 + mt * 16 + il) * 64 + kk * 32 + q4 * 8];

  const short8 ones8 = { 0x3F80, 0x3F80, 0x3F80, 0x3F80,
                         0x3F80, 0x3F80, 0x3F80, 0x3F80 };  // bf16 1.0 x8

  f32x4 oaccT[2][4];                // [mt][ct]: O^T[c][t], c=ct*16+q4*4+r, t=mt*16+il
  f32x4 lacc[2];                    // denominator via ones-MFMA (all rows equal)
  #pragma unroll
  for (int mt = 0; mt < 2; mt++) {
    lacc[mt] = (f32x4){0.f, 0.f, 0.f, 0.f};
    #pragma unroll
    for (int ct = 0; ct < 4; ct++) oaccT[mt][ct] = (f32x4){0.f, 0.f, 0.f, 0.f};
  }

  // prefetch tile 0 into registers
  short8 kreg0 = *(const short8*)&kt[nbase + (size_t)srow0 * 64 + scol];
  short8 kreg1 = *(const short8*)&kt[nbase + (size_t)srow1 * 64 + scol];
  short8 vreg0 = *(const short8*)&v[nbase + (size_t)srow0 * TT + scol];
  short8 vreg1 = *(const short8*)&v[nbase + (size_t)srow1 * TT + scol];

  #pragma unroll 1
  for (int st = 0; st < 16; st++) {
    __syncthreads();                     // prev-iter compute reads of ks/vs done
    *(short8*)&ks[srow0 * 72 + scol] = kreg0;
    *(short8*)&ks[srow1 * 72 + scol] = kreg1;
    *(short8*)&vs[srow0 * 72 + scol] = vreg0;
    *(short8*)&vs[srow1 * 72 + scol] = vreg1;
    if (st < 15) {                       // prefetch st+1: in flight across barrier
      const int s1 = (st + 1) * 64;
      kreg0 = *(const short8*)&kt[nbase + (size_t)(s1 + srow0) * 64 + scol];
      kreg1 = *(const short8*)&kt[nbase + (size_t)(s1 + srow1) * 64 + scol];
      vreg0 = *(const short8*)&v[nbase + (size_t)srow0 * TT + s1 + scol];
      vreg1 = *(const short8*)&v[nbase + (size_t)srow1 * TT + s1 + scol];
    }
    __syncthreads();                     // ks/vs visible

    // ---- phase 1: S^T + exp -> P packed directly into K=32 B-frag halves.
    // pq[mt][u] word (st2&1)*2+p holds bf16 pair (P[s=q4*4+2p..+1][t]) of
    // strip st2 = 2u+(st2&1): k=q4*8+j maps to s=(j>>2)*16+q4*4+(j&3).
    uint4v pq[2][2];
    #pragma unroll
    for (int st2 = 0; st2 < 4; st2++) {
      short8 ka0 = *(const short8*)&ks[(st2 * 16 + il) * 72 + q4 * 8];
      short8 ka1 = *(const short8*)&ks[(st2 * 16 + il) * 72 + 32 + q4 * 8];
      #pragma unroll
      for (int mt = 0; mt < 2; mt++) {
        f32x4 sT = (f32x4){0.f, 0.f, 0.f, 0.f};
        sT = mfma32(ka0, qb[mt][0], sT);
        sT = mfma32(ka1, qb[mt][1], sT);
        float p0 = EXP2(sT[0]), p1 = EXP2(sT[1]), p2 = EXP2(sT[2]), p3 = EXP2(sT[3]);
        pq[mt][st2 >> 1][(st2 & 1) * 2]     = packbf2(rnd_u(p1), rnd_u(p0));
        pq[mt][st2 >> 1][(st2 & 1) * 2 + 1] = packbf2(rnd_u(p3), rnd_u(p2));
      }
    }
    short8 pb[2][2];                  // [mt][u]: K=32 B-frag for strip pair u
    #pragma unroll
    for (int mt = 0; mt < 2; mt++)
      #pragma unroll
      for (int u = 0; u < 2; u++) {
        pb[mt][u] = __builtin_bit_cast(short8, pq[mt][u]);
        lacc[mt] = mfma32(ones8, pb[mt][u], lacc[mt]);   // row-sum, K=32
      }

    // ---- phase 2: PV at K=32; permuted vs: h0/h1 ARE the strip-pair A-frags
    #pragma unroll
    for (int ct = 0; ct < 4; ct++) {
      short8 h0 = *(const short8*)&vs[(ct * 16 + il) * 72 + q4 * 16];
      short8 h1 = *(const short8*)&vs[(ct * 16 + il) * 72 + q4 * 16 + 8];
      #pragma unroll
      for (int mt = 0; mt < 2; mt++) {
        oaccT[mt][ct] = mfma32(h0, pb[mt][0], oaccT[mt][ct]);
        oaccT[mt][ct] = mfma32(h1, pb[mt][1], oaccT[mt][ct]);
      }
    }
  }

  // ================= epilogue ==============================================
  // l comes from lacc (all 4 rows equal = full sum over s for col t=il)
  float linv[2];
  #pragma unroll
  for (int mt = 0; mt < 2; mt++) linv[mt] = 1.f / lacc[mt][0];

  // O^T regs -> bf16 K=32 B-frags: concat of ct-pair (2u, 2u+1)
  uint4v obq[2][2];
  #pragma unroll
  for (int mt = 0; mt < 2; mt++)
    #pragma unroll
    for (int ct = 0; ct < 4; ct++) {
      float a = oaccT[mt][ct][0] * linv[mt], b = oaccT[mt][ct][1] * linv[mt];
      float c = oaccT[mt][ct][2] * linv[mt], d = oaccT[mt][ct][3] * linv[mt];
      obq[mt][ct >> 1][(ct & 1) * 2]     = packbf2(rnd_u(b), rnd_u(a));
      obq[mt][ct >> 1][(ct & 1) * 2 + 1] = packbf2(rnd_u(d), rnd_u(c));
    }
  short8 ob8[2][2];
  #pragma unroll
  for (int mt = 0; mt < 2; mt++)
    #pragma unroll
    for (int u = 0; u < 2; u++)
      ob8[mt][u] = __builtin_bit_cast(short8, obq[mt][u]);

  __syncthreads();   // all PV reads of ks/vs done before obuf overwrites them

  // res[o][t] = Wo(A) x O(B) at K=32 -> obuf[o][t_local] (fp32, stride 132)
  // wob is pre-permuted: one short8 = full K=32 A-frag per c-pair u.
  #pragma unroll
  for (int ot = 0; ot < 4; ot++) {
    short8 wa0 = *(const short8*)&wob[(ot * 16 + il) * 64 + q4 * 8];
    short8 wa1 = *(const short8*)&wob[(ot * 16 + il) * 64 + 32 + q4 * 8];
    #pragma unroll
    for (int mt = 0; mt < 2; mt++) {
      f32x4 res = (f32x4){0.f, 0.f, 0.f, 0.f};
      res = mfma32(wa0, ob8[mt][0], res);
      res = mfma32(wa1, ob8[mt][1], res);
      #pragma unroll
      for (int r = 0; r < 4; r++)
        obuf[(ot * 16 + q4 * 4 + r) * 132 + w * 32 + mt * 16 + il] = res[r];
    }
  }
  __syncthreads();

  // coalesced store + residual: full 128B lines (8-lane groups x float4)
  const int orow = tid >> 3;          // 0..31
  const int ocb  = (tid & 7) * 4;     // col base
  #pragma unroll
  for (int half = 0; half < 2; half++) {
    const int row = orow + half * 32;
    #pragma unroll
    for (int k = 0; k < 4; k++) {
      const int col = ocb + k * 32;
      float4 val = *(const float4*)&obuf[row * 132 + col];
      const size_t idx = nbase + (size_t)row * TT + qt0 + col;
      float4 xv = *(const float4*)&x[idx];
      val.x += xv.x; val.y += xv.y; val.z += xv.z; val.w += xv.w;
      *(float4*)&out[idx] = val;
    }
  }
}

// ---------------------------------------------------------------------------
extern "C" void kernel_launch(void* const* d_in, const int* in_sizes, int n_in,
                              void* d_out, int out_size, void* d_ws, size_t ws_size,
                              hipStream_t stream) {
  const float* x     = (const float*)d_in[0];
  const float* Wq    = (const float*)d_in[1];
  const float* Wk    = (const float*)d_in[2];
  const float* Wv    = (const float*)d_in[3];
  const float* Wo    = (const float*)d_in[4];
  const float* scale = (const float*)d_in[5];
  float* out = (float*)d_out;

  const size_t elems = (size_t)NB * CC * TT;
  bf16* wb  = (bf16*)d_ws;          // 16384 bf16 weights
  bf16* qtb = wb + 16384;
  bf16* ktb = qtb + elems;
  bf16* vv  = ktb + elems;

  wcvt<<<64, 256, 0, stream>>>(Wq, Wk, Wv, Wo, scale, wb);
  qkv_mfma<<<dim3(TT / 64, NB), 256, 0, stream>>>(x, wb, qtb, ktb, vv);
  attn_flash<<<dim3(NB * (TT / 128)), 256, 0, stream>>>(qtb, ktb, vv, wb + 12288, x, out);
}

// Round 3
// 157.319 us; speedup vs baseline: 1.0525x; 1.0065x over previous
//
#include <hip/hip_runtime.h>
#include <hip/hip_bf16.h>

typedef __hip_bfloat16 bf16;
typedef __attribute__((ext_vector_type(8))) short short8;   // 8 bf16 = K=32 MFMA A/B frag
typedef __attribute__((ext_vector_type(4))) short short4v;  // 4 bf16 = K=16 MFMA A/B frag
typedef __attribute__((ext_vector_type(4))) float f32x4;    // MFMA C/D frag
typedef __attribute__((ext_vector_type(4))) unsigned uint4v;

#define NB 128   // B*TO
#define CC 64    // channels
#define TT 1024  // time

#if __has_builtin(__builtin_amdgcn_exp2f)
#define EXP2(x) __builtin_amdgcn_exp2f(x)
#else
#define EXP2(x) exp2f(x)
#endif

// ---- cheap bf16 conversion: round-half-up via +0x8000, pack 2 per v_perm ---
__device__ __forceinline__ unsigned rnd_u(float f) {
  return __builtin_bit_cast(unsigned, f) + 0x8000u;
}
__device__ __forceinline__ short f2bfs_fast(float f) {
  return (short)(rnd_u(f) >> 16);
}
__device__ __forceinline__ unsigned packbf2(unsigned uhi, unsigned ulo) {
  return __builtin_amdgcn_perm(uhi, ulo, 0x07060302);
}
__device__ __forceinline__ short4v pack4(float a, float b, float c, float d) {
  unsigned pd[2] = { packbf2(rnd_u(b), rnd_u(a)), packbf2(rnd_u(d), rnd_u(c)) };
  return *(const short4v*)pd;
}

__device__ __forceinline__ f32x4 mfma32(short8 a, short8 b, f32x4 c) {
  return __builtin_amdgcn_mfma_f32_16x16x32_bf16(a, b, c, 0, 0, 0);
}

// ---------------------------------------------------------------------------
// Kernel 0: weight convert fp32->bf16 (one-time). Wq PRE-SCALED by
// scale*log2(e) so scores feed exp2 directly.
// Wo is stored PERMUTED so the attn epilogue's K=32 A-frag is one
// contiguous short8: position o*64 + u*32 + q4*8 + j holds
// Wo[o][(2u+(j>>2))*16 + q4*4 + (j&3)].
// ---------------------------------------------------------------------------
__global__ __launch_bounds__(256) void wcvt(
    const float* __restrict__ Wq, const float* __restrict__ Wk,
    const float* __restrict__ Wv, const float* __restrict__ Wo,
    const float* __restrict__ scale_p, bf16* __restrict__ wb)
{
  const int i = blockIdx.x * 256 + threadIdx.x;
  float f;
  if      (i <  4096) f = Wq[i] * (*scale_p) * 1.44269504089f;
  else if (i <  8192) f = Wk[i - 4096];
  else if (i < 12288) f = Wv[i - 8192];
  else {
    const int ii = i - 12288;
    const int o  = ii >> 6;
    const int cp = ii & 63;                       // permuted column position
    const int u  = cp >> 5, q4 = (cp >> 3) & 3, j = cp & 7;
    const int c  = (2 * u + (j >> 2)) * 16 + q4 * 4 + (j & 3);
    f = Wo[o * 64 + c];
  }
  wb[i] = __float2bfloat16(f);
}

// ---------------------------------------------------------------------------
// Kernel 1: MFMA q/k/v projections. qt/kt in [n][t][c].
// V is written in a PERMUTED [n][c][s'] layout: within each 64-s block,
// s = a*16+b*4+j is stored at s' = b*16+a*4+j. One b128 read from LDS then
// yields the K=32 PV A-frag for a strip PAIR.
// ---------------------------------------------------------------------------
__global__ __launch_bounds__(256) void qkv_mfma(
    const float* __restrict__ x, const bf16* __restrict__ wb,
    bf16* __restrict__ qt, bf16* __restrict__ kt, bf16* __restrict__ v)
{
  __shared__ short xs[64 * 72];   // x^T tile [t][c]
  __shared__ short ys[64 * 72];   // output assembly buffer

  const int n  = blockIdx.y;
  const int t0 = blockIdx.x * 64;
  const int tid = threadIdx.x;
  const int w  = tid >> 6, il = tid & 15, q4 = (tid & 63) >> 4;
  const size_t nbase = (size_t)n * (CC * TT);

  {
    const int tc = tid & 15;
    const int c0 = (tid >> 4) * 4;
    float fe[4][4];
    #pragma unroll
    for (int j = 0; j < 4; j++) {
      float4 fj = *(const float4*)&x[nbase + (size_t)(c0 + j) * TT + t0 + tc * 4];
      fe[j][0] = fj.x; fe[j][1] = fj.y; fe[j][2] = fj.z; fe[j][3] = fj.w;
    }
    #pragma unroll
    for (int e = 0; e < 4; e++)
      *(short4v*)&xs[(tc * 4 + e) * 72 + c0] = pack4(fe[0][e], fe[1][e], fe[2][e], fe[3][e]);
  }
  __syncthreads();

  short8 xa[2];
  #pragma unroll
  for (int kk = 0; kk < 2; kk++)
    xa[kk] = *(const short8*)&xs[(w * 16 + il) * 72 + kk * 32 + q4 * 8];

  const bf16* wq = wb;
  const bf16* wk = wb + 4096;
  const bf16* wv = wb + 8192;

  f32x4 aq[4], ak[4], av[4];
  #pragma unroll
  for (int i = 0; i < 4; i++) {
    aq[i] = (f32x4){0.f,0.f,0.f,0.f};
    ak[i] = (f32x4){0.f,0.f,0.f,0.f};
    av[i] = (f32x4){0.f,0.f,0.f,0.f};
  }

  #pragma unroll
  for (int kk = 0; kk < 2; kk++) {
    #pragma unroll
    for (int ot = 0; ot < 4; ot++) {
      const int ridx = (ot * 16 + il) * 64 + kk * 32 + q4 * 8;
      short8 bq = *(const short8*)&wq[ridx];
      short8 bk = *(const short8*)&wk[ridx];
      short8 bv = *(const short8*)&wv[ridx];
      aq[ot] = mfma32(xa[kk], bq, aq[ot]);   // D[t][o]
      ak[ot] = mfma32(xa[kk], bk, ak[ot]);   // D[t][o]
      av[ot] = mfma32(bv, xa[kk], av[ot]);   // D[o][t]
    }
  }

  const int rr = tid >> 2;
  const int sg = (tid & 3) * 8;

  __syncthreads();
  #pragma unroll
  for (int ot = 0; ot < 4; ot++)
    #pragma unroll
    for (int r = 0; r < 4; r++)
      ys[(w * 16 + q4 * 4 + r) * 72 + ot * 16 + il] = f2bfs_fast(aq[ot][r]);
  __syncthreads();
  *(short8*)&qt[nbase + (size_t)(t0 + rr) * 64 + sg]      = *(const short8*)&ys[rr * 72 + sg];
  *(short8*)&qt[nbase + (size_t)(t0 + rr) * 64 + sg + 32] = *(const short8*)&ys[rr * 72 + sg + 32];

  __syncthreads();
  #pragma unroll
  for (int ot = 0; ot < 4; ot++)
    #pragma unroll
    for (int r = 0; r < 4; r++)
      ys[(w * 16 + q4 * 4 + r) * 72 + ot * 16 + il] = f2bfs_fast(ak[ot][r]);
  __syncthreads();
  *(short8*)&kt[nbase + (size_t)(t0 + rr) * 64 + sg]      = *(const short8*)&ys[rr * 72 + sg];
  *(short8*)&kt[nbase + (size_t)(t0 + rr) * 64 + sg + 32] = *(const short8*)&ys[rr * 72 + sg + 32];

  __syncthreads();
  // V with permuted s-column: t_local = w*16+il -> col (il>>2)*16 + w*4 + (il&3)
  #pragma unroll
  for (int ot = 0; ot < 4; ot++)
    #pragma unroll
    for (int r = 0; r < 4; r++)
      ys[(ot * 16 + q4 * 4 + r) * 72 + (il >> 2) * 16 + w * 4 + (il & 3)] =
          f2bfs_fast(av[ot][r]);
  __syncthreads();
  *(short8*)&v[nbase + (size_t)rr * TT + t0 + sg]      = *(const short8*)&ys[rr * 72 + sg];
  *(short8*)&v[nbase + (size_t)rr * TT + t0 + sg + 32] = *(const short8*)&ys[rr * 72 + sg + 32];
}

// ---------------------------------------------------------------------------
// Kernel 2: flash attention + Wo + residual.
// r14 change: t-per-wave 32 -> 64 (block covers 256 t, grid 1024 -> 512).
// Rationale: LDS was the top pipe (~60% busy incl. 4.46M conflict cycles);
// each wave reads the whole K/V tile per iter, so fragment traffic per
// t-column is halved by doubling t ownership. Total MFMA/VALU work is
// unchanged; per-CU LDS traffic and barrier count halve. Grid 512 = 2
// blocks/CU resident (launch_bounds (256,2): VGPR up to 256, ~200 used).
// obuf grows to 64x260 fp32 (66.5 KB); stride 260 = 4 mod 32 keeps every
// LDS access at the proven conflict-minimum patterns.
// Layouts (m89/m120-verified): A[m=lane&15][k=quad*8+j];
// B[k=quad*8+j][n=lane&15]; C/D row=quad*4+reg, col=lane&15.
// ---------------------------------------------------------------------------
__global__ __launch_bounds__(256, 2) void attn_flash(
    const bf16* __restrict__ qt, const bf16* __restrict__ kt,
    const bf16* __restrict__ v,  const bf16* __restrict__ wob,
    const float* __restrict__ x, float* __restrict__ out)
{
  __shared__ float obuf[64 * 260];          // 66560 B; ks/vs alias the front
  short* ks = (short*)obuf;                 // K tile [s][c]     (9216 B)
  short* vs = ks + 64 * 72;                 // V tile [c][s']    (9216 B)

  const int bid = blockIdx.x;
  const int n   = bid & 127;        // bid%8 == n%8 -> same-n blocks share an XCD
  const int qt0 = (bid >> 7) * 256;
  const int tid = threadIdx.x;
  const int w   = tid >> 6;
  const int il  = tid & 15;
  const int q4  = (tid & 63) >> 4;
  const size_t nbase = (size_t)n * (CC * TT);

  // staging coords: 2 chunks of 16B each for K and V
  const int srow0 = tid >> 3, scol = (tid & 7) * 8;
  const int srow1 = srow0 + 32;

  // persistent Q B-frags (pre-scaled): B[k=c][n=t], wave's 64 queries
  short8 qb[4][2];
  #pragma unroll
  for (int mt = 0; mt < 4; mt++)
    #pragma unroll
    for (int kk = 0; kk < 2; kk++)
      qb[mt][kk] = *(const short8*)&qt[nbase +
          (size_t)(qt0 + w * 64 + mt * 16 + il) * 64 + kk * 32 + q4 * 8];

  const short8 ones8 = { 0x3F80, 0x3F80, 0x3F80, 0x3F80,
                         0x3F80, 0x3F80, 0x3F80, 0x3F80 };  // bf16 1.0 x8

  f32x4 oaccT[4][4];                // [mt][ct]: O^T[c][t], c=ct*16+q4*4+r, t=mt*16+il
  f32x4 lacc[4];                    // denominator via ones-MFMA (all rows equal)
  #pragma unroll
  for (int mt = 0; mt < 4; mt++) {
    lacc[mt] = (f32x4){0.f, 0.f, 0.f, 0.f};
    #pragma unroll
    for (int ct = 0; ct < 4; ct++) oaccT[mt][ct] = (f32x4){0.f, 0.f, 0.f, 0.f};
  }

  // prefetch tile 0 into registers
  short8 kreg0 = *(const short8*)&kt[nbase + (size_t)srow0 * 64 + scol];
  short8 kreg1 = *(const short8*)&kt[nbase + (size_t)srow1 * 64 + scol];
  short8 vreg0 = *(const short8*)&v[nbase + (size_t)srow0 * TT + scol];
  short8 vreg1 = *(const short8*)&v[nbase + (size_t)srow1 * TT + scol];

  #pragma unroll 1
  for (int st = 0; st < 16; st++) {
    __syncthreads();                     // prev-iter compute reads of ks/vs done
    *(short8*)&ks[srow0 * 72 + scol] = kreg0;
    *(short8*)&ks[srow1 * 72 + scol] = kreg1;
    *(short8*)&vs[srow0 * 72 + scol] = vreg0;
    *(short8*)&vs[srow1 * 72 + scol] = vreg1;
    if (st < 15) {                       // prefetch st+1: in flight across barrier
      const int s1 = (st + 1) * 64;
      kreg0 = *(const short8*)&kt[nbase + (size_t)(s1 + srow0) * 64 + scol];
      kreg1 = *(const short8*)&kt[nbase + (size_t)(s1 + srow1) * 64 + scol];
      vreg0 = *(const short8*)&v[nbase + (size_t)srow0 * TT + s1 + scol];
      vreg1 = *(const short8*)&v[nbase + (size_t)srow1 * TT + s1 + scol];
    }
    __syncthreads();                     // ks/vs visible

    // ---- phase 1: S^T + exp -> P packed directly into K=32 B-frag halves.
    // pq[mt][u] word (st2&1)*2+p holds bf16 pair (P[s=q4*4+2p..+1][t]) of
    // strip st2 = 2u+(st2&1): k=q4*8+j maps to s=(j>>2)*16+q4*4+(j&3).
    uint4v pq[4][2];
    #pragma unroll
    for (int st2 = 0; st2 < 4; st2++) {
      short8 ka0 = *(const short8*)&ks[(st2 * 16 + il) * 72 + q4 * 8];
      short8 ka1 = *(const short8*)&ks[(st2 * 16 + il) * 72 + 32 + q4 * 8];
      #pragma unroll
      for (int mt = 0; mt < 4; mt++) {
        f32x4 sT = (f32x4){0.f, 0.f, 0.f, 0.f};
        sT = mfma32(ka0, qb[mt][0], sT);
        sT = mfma32(ka1, qb[mt][1], sT);
        float p0 = EXP2(sT[0]), p1 = EXP2(sT[1]), p2 = EXP2(sT[2]), p3 = EXP2(sT[3]);
        pq[mt][st2 >> 1][(st2 & 1) * 2]     = packbf2(rnd_u(p1), rnd_u(p0));
        pq[mt][st2 >> 1][(st2 & 1) * 2 + 1] = packbf2(rnd_u(p3), rnd_u(p2));
      }
    }
    short8 pb[4][2];                  // [mt][u]: K=32 B-frag for strip pair u
    #pragma unroll
    for (int mt = 0; mt < 4; mt++)
      #pragma unroll
      for (int u = 0; u < 2; u++) {
        pb[mt][u] = __builtin_bit_cast(short8, pq[mt][u]);
        lacc[mt] = mfma32(ones8, pb[mt][u], lacc[mt]);   // row-sum, K=32
      }

    // ---- phase 2: PV at K=32; permuted vs: h0/h1 ARE the strip-pair A-frags
    #pragma unroll
    for (int ct = 0; ct < 4; ct++) {
      short8 h0 = *(const short8*)&vs[(ct * 16 + il) * 72 + q4 * 16];
      short8 h1 = *(const short8*)&vs[(ct * 16 + il) * 72 + q4 * 16 + 8];
      #pragma unroll
      for (int mt = 0; mt < 4; mt++) {
        oaccT[mt][ct] = mfma32(h0, pb[mt][0], oaccT[mt][ct]);
        oaccT[mt][ct] = mfma32(h1, pb[mt][1], oaccT[mt][ct]);
      }
    }
  }

  // ================= epilogue ==============================================
  // l comes from lacc (all 4 rows equal = full sum over s for col t=il)
  float linv[4];
  #pragma unroll
  for (int mt = 0; mt < 4; mt++) linv[mt] = 1.f / lacc[mt][0];

  // O^T regs -> bf16 K=32 B-frags: concat of ct-pair (2u, 2u+1)
  uint4v obq[4][2];
  #pragma unroll
  for (int mt = 0; mt < 4; mt++)
    #pragma unroll
    for (int ct = 0; ct < 4; ct++) {
      float a = oaccT[mt][ct][0] * linv[mt], b = oaccT[mt][ct][1] * linv[mt];
      float c = oaccT[mt][ct][2] * linv[mt], d = oaccT[mt][ct][3] * linv[mt];
      obq[mt][ct >> 1][(ct & 1) * 2]     = packbf2(rnd_u(b), rnd_u(a));
      obq[mt][ct >> 1][(ct & 1) * 2 + 1] = packbf2(rnd_u(d), rnd_u(c));
    }
  short8 ob8[4][2];
  #pragma unroll
  for (int mt = 0; mt < 4; mt++)
    #pragma unroll
    for (int u = 0; u < 2; u++)
      ob8[mt][u] = __builtin_bit_cast(short8, obq[mt][u]);

  __syncthreads();   // all PV reads of ks/vs done before obuf overwrites them

  // res[o][t] = Wo(A) x O(B) at K=32 -> obuf[o][t_local] (fp32, stride 260)
  // wob is pre-permuted: one short8 = full K=32 A-frag per c-pair u.
  #pragma unroll
  for (int ot = 0; ot < 4; ot++) {
    short8 wa0 = *(const short8*)&wob[(ot * 16 + il) * 64 + q4 * 8];
    short8 wa1 = *(const short8*)&wob[(ot * 16 + il) * 64 + 32 + q4 * 8];
    #pragma unroll
    for (int mt = 0; mt < 4; mt++) {
      f32x4 res = (f32x4){0.f, 0.f, 0.f, 0.f};
      res = mfma32(wa0, ob8[mt][0], res);
      res = mfma32(wa1, ob8[mt][1], res);
      #pragma unroll
      for (int r = 0; r < 4; r++)
        obuf[(ot * 16 + q4 * 4 + r) * 260 + w * 64 + mt * 16 + il] = res[r];
    }
  }
  __syncthreads();

  // coalesced store + residual: full 128B lines (8-lane groups x float4)
  const int orow = tid >> 3;          // 0..31
  const int ocb  = (tid & 7) * 4;     // col base
  #pragma unroll
  for (int half = 0; half < 2; half++) {
    const int row = orow + half * 32;
    #pragma unroll
    for (int k = 0; k < 8; k++) {
      const int col = ocb + k * 32;
      float4 val = *(const float4*)&obuf[row * 260 + col];
      const size_t idx = nbase + (size_t)row * TT + qt0 + col;
      float4 xv = *(const float4*)&x[idx];
      val.x += xv.x; val.y += xv.y; val.z += xv.z; val.w += xv.w;
      *(float4*)&out[idx] = val;
    }
  }
}

// ---------------------------------------------------------------------------
extern "C" void kernel_launch(void* const* d_in, const int* in_sizes, int n_in,
                              void* d_out, int out_size, void* d_ws, size_t ws_size,
                              hipStream_t stream) {
  const float* x     = (const float*)d_in[0];
  const float* Wq    = (const float*)d_in[1];
  const float* Wk    = (const float*)d_in[2];
  const float* Wv    = (const float*)d_in[3];
  const float* Wo    = (const float*)d_in[4];
  const float* scale = (const float*)d_in[5];
  float* out = (float*)d_out;

  const size_t elems = (size_t)NB * CC * TT;
  bf16* wb  = (bf16*)d_ws;          // 16384 bf16 weights
  bf16* qtb = wb + 16384;
  bf16* ktb = qtb + elems;
  bf16* vv  = ktb + elems;

  wcvt<<<64, 256, 0, stream>>>(Wq, Wk, Wv, Wo, scale, wb);
  qkv_mfma<<<dim3(TT / 64, NB), 256, 0, stream>>>(x, wb, qtb, ktb, vv);
  attn_flash<<<dim3(NB * (TT / 256)), 256, 0, stream>>>(qtb, ktb, vv, wb + 12288, x, out);
}

// Round 4
// 156.891 us; speedup vs baseline: 1.0554x; 1.0027x over previous
//
#include <hip/hip_runtime.h>
#include <hip/hip_bf16.h>

typedef __hip_bfloat16 bf16;
typedef __attribute__((ext_vector_type(8))) short short8;   // 8 bf16 = K=32 MFMA A/B frag
typedef __attribute__((ext_vector_type(4))) short short4v;  // 4 bf16 = K=16 MFMA A/B frag
typedef __attribute__((ext_vector_type(4))) float f32x4;    // MFMA C/D frag
typedef __attribute__((ext_vector_type(4))) unsigned uint4v;

#define NB 128   // B*TO
#define CC 64    // channels
#define TT 1024  // time

#if __has_builtin(__builtin_amdgcn_exp2f)
#define EXP2(x) __builtin_amdgcn_exp2f(x)
#else
#define EXP2(x) exp2f(x)
#endif

// ---- cheap bf16 conversion: round-half-up via +0x8000, pack 2 per v_perm ---
__device__ __forceinline__ unsigned rnd_u(float f) {
  return __builtin_bit_cast(unsigned, f) + 0x8000u;
}
__device__ __forceinline__ short f2bfs_fast(float f) {
  return (short)(rnd_u(f) >> 16);
}
__device__ __forceinline__ unsigned packbf2(unsigned uhi, unsigned ulo) {
  return __builtin_amdgcn_perm(uhi, ulo, 0x07060302);
}
__device__ __forceinline__ short4v pack4(float a, float b, float c, float d) {
  unsigned pd[2] = { packbf2(rnd_u(b), rnd_u(a)), packbf2(rnd_u(d), rnd_u(c)) };
  return *(const short4v*)pd;
}

__device__ __forceinline__ f32x4 mfma32(short8 a, short8 b, f32x4 c) {
  return __builtin_amdgcn_mfma_f32_16x16x32_bf16(a, b, c, 0, 0, 0);
}

// ---------------------------------------------------------------------------
// Kernel 0: weight convert fp32->bf16 (one-time). Wq PRE-SCALED by
// scale*log2(e) so scores feed exp2 directly.
// Wo is stored PERMUTED so the attn epilogue's K=32 A-frag is one
// contiguous short8: position o*64 + u*32 + q4*8 + j holds
// Wo[o][(2u+(j>>2))*16 + q4*4 + (j&3)].
// ---------------------------------------------------------------------------
__global__ __launch_bounds__(256) void wcvt(
    const float* __restrict__ Wq, const float* __restrict__ Wk,
    const float* __restrict__ Wv, const float* __restrict__ Wo,
    const float* __restrict__ scale_p, bf16* __restrict__ wb)
{
  const int i = blockIdx.x * 256 + threadIdx.x;
  float f;
  if      (i <  4096) f = Wq[i] * (*scale_p) * 1.44269504089f;
  else if (i <  8192) f = Wk[i - 4096];
  else if (i < 12288) f = Wv[i - 8192];
  else {
    const int ii = i - 12288;
    const int o  = ii >> 6;
    const int cp = ii & 63;                       // permuted column position
    const int u  = cp >> 5, q4 = (cp >> 3) & 3, j = cp & 7;
    const int c  = (2 * u + (j >> 2)) * 16 + q4 * 4 + (j & 3);
    f = Wo[o * 64 + c];
  }
  wb[i] = __float2bfloat16(f);
}

// ---------------------------------------------------------------------------
// Kernel 1: MFMA q/k/v projections. qt/kt in [n][t][c].
// V is written in a PERMUTED [n][c][s'] layout: within each 64-s block,
// s = a*16+b*4+j is stored at s' = b*16+a*4+j. One b128 read from LDS then
// yields the K=32 PV A-frag for a strip PAIR.
// ---------------------------------------------------------------------------
__global__ __launch_bounds__(256) void qkv_mfma(
    const float* __restrict__ x, const bf16* __restrict__ wb,
    bf16* __restrict__ qt, bf16* __restrict__ kt, bf16* __restrict__ v)
{
  __shared__ short xs[64 * 72];   // x^T tile [t][c]
  __shared__ short ys[64 * 72];   // output assembly buffer

  const int n  = blockIdx.y;
  const int t0 = blockIdx.x * 64;
  const int tid = threadIdx.x;
  const int w  = tid >> 6, il = tid & 15, q4 = (tid & 63) >> 4;
  const size_t nbase = (size_t)n * (CC * TT);

  {
    const int tc = tid & 15;
    const int c0 = (tid >> 4) * 4;
    float fe[4][4];
    #pragma unroll
    for (int j = 0; j < 4; j++) {
      float4 fj = *(const float4*)&x[nbase + (size_t)(c0 + j) * TT + t0 + tc * 4];
      fe[j][0] = fj.x; fe[j][1] = fj.y; fe[j][2] = fj.z; fe[j][3] = fj.w;
    }
    #pragma unroll
    for (int e = 0; e < 4; e++)
      *(short4v*)&xs[(tc * 4 + e) * 72 + c0] = pack4(fe[0][e], fe[1][e], fe[2][e], fe[3][e]);
  }
  __syncthreads();

  short8 xa[2];
  #pragma unroll
  for (int kk = 0; kk < 2; kk++)
    xa[kk] = *(const short8*)&xs[(w * 16 + il) * 72 + kk * 32 + q4 * 8];

  const bf16* wq = wb;
  const bf16* wk = wb + 4096;
  const bf16* wv = wb + 8192;

  f32x4 aq[4], ak[4], av[4];
  #pragma unroll
  for (int i = 0; i < 4; i++) {
    aq[i] = (f32x4){0.f,0.f,0.f,0.f};
    ak[i] = (f32x4){0.f,0.f,0.f,0.f};
    av[i] = (f32x4){0.f,0.f,0.f,0.f};
  }

  #pragma unroll
  for (int kk = 0; kk < 2; kk++) {
    #pragma unroll
    for (int ot = 0; ot < 4; ot++) {
      const int ridx = (ot * 16 + il) * 64 + kk * 32 + q4 * 8;
      short8 bq = *(const short8*)&wq[ridx];
      short8 bk = *(const short8*)&wk[ridx];
      short8 bv = *(const short8*)&wv[ridx];
      aq[ot] = mfma32(xa[kk], bq, aq[ot]);   // D[t][o]
      ak[ot] = mfma32(xa[kk], bk, ak[ot]);   // D[t][o]
      av[ot] = mfma32(bv, xa[kk], av[ot]);   // D[o][t]
    }
  }

  const int rr = tid >> 2;
  const int sg = (tid & 3) * 8;

  __syncthreads();
  #pragma unroll
  for (int ot = 0; ot < 4; ot++)
    #pragma unroll
    for (int r = 0; r < 4; r++)
      ys[(w * 16 + q4 * 4 + r) * 72 + ot * 16 + il] = f2bfs_fast(aq[ot][r]);
  __syncthreads();
  *(short8*)&qt[nbase + (size_t)(t0 + rr) * 64 + sg]      = *(const short8*)&ys[rr * 72 + sg];
  *(short8*)&qt[nbase + (size_t)(t0 + rr) * 64 + sg + 32] = *(const short8*)&ys[rr * 72 + sg + 32];

  __syncthreads();
  #pragma unroll
  for (int ot = 0; ot < 4; ot++)
    #pragma unroll
    for (int r = 0; r < 4; r++)
      ys[(w * 16 + q4 * 4 + r) * 72 + ot * 16 + il] = f2bfs_fast(ak[ot][r]);
  __syncthreads();
  *(short8*)&kt[nbase + (size_t)(t0 + rr) * 64 + sg]      = *(const short8*)&ys[rr * 72 + sg];
  *(short8*)&kt[nbase + (size_t)(t0 + rr) * 64 + sg + 32] = *(const short8*)&ys[rr * 72 + sg + 32];

  __syncthreads();
  // V with permuted s-column: t_local = w*16+il -> col (il>>2)*16 + w*4 + (il&3)
  #pragma unroll
  for (int ot = 0; ot < 4; ot++)
    #pragma unroll
    for (int r = 0; r < 4; r++)
      ys[(ot * 16 + q4 * 4 + r) * 72 + (il >> 2) * 16 + w * 4 + (il & 3)] =
          f2bfs_fast(av[ot][r]);
  __syncthreads();
  *(short8*)&v[nbase + (size_t)rr * TT + t0 + sg]      = *(const short8*)&ys[rr * 72 + sg];
  *(short8*)&v[nbase + (size_t)rr * TT + t0 + sg + 32] = *(const short8*)&ys[rr * 72 + sg + 32];
}

// ---------------------------------------------------------------------------
// Kernel 2: flash attention + Wo + residual.
// r15: REVERT to r13 geometry (32 t/wave, grid 1024, 4 blocks/CU — r14's
// 64 t/wave halved LDS traffic but dropped occupancy 27->16% and REGRESSED
// 48.9->53.9us: the kernel is latency/barrier-bound, not LDS-BW-bound).
// Change: DOUBLE-BUFFERED K/V staging removes barrier #1 (the wait for
// prev-iter reads before overwriting the single buffer). Each iter writes
// buf[cur^1] while computing from buf[cur]; ONE __syncthreads per iter
// (16 barriers instead of 32, each a full waitcnt drain). LDS 36.9 KB/block
// (obuf aliases the staging region), still 4 blocks/CU (147.5 KB < 160 KB).
// Instruction mix unchanged vs r13 — pure stall-structure change.
// Layouts (m89/m120-verified): A[m=lane&15][k=quad*8+j];
// B[k=quad*8+j][n=lane&15]; C/D row=quad*4+reg, col=lane&15.
// ---------------------------------------------------------------------------
__global__ __launch_bounds__(256, 4) void attn_flash(
    const bf16* __restrict__ qt, const bf16* __restrict__ kt,
    const bf16* __restrict__ v,  const bf16* __restrict__ wob,
    const float* __restrict__ x, float* __restrict__ out)
{
  // double-buffered staging: [buf][ ks(4608 shorts) | vs(4608 shorts) ]
  __shared__ short stage[2 * 9216];         // 36864 B
  float* obuf = (float*)stage;              // epilogue alias (33792 B, stride 132)

  const int bid = blockIdx.x;
  const int n   = bid & 127;        // bid%8 == n%8 -> same-n blocks share an XCD
  const int qt0 = (bid >> 7) * 128;
  const int tid = threadIdx.x;
  const int w   = tid >> 6;
  const int il  = tid & 15;
  const int q4  = (tid & 63) >> 4;
  const size_t nbase = (size_t)n * (CC * TT);

  // staging coords: 2 chunks of 16B each for K and V
  const int srow0 = tid >> 3, scol = (tid & 7) * 8;
  const int srow1 = srow0 + 32;

  // persistent Q B-frags (pre-scaled): B[k=c][n=t], wave's 32 queries
  short8 qb[2][2];
  #pragma unroll
  for (int mt = 0; mt < 2; mt++)
    #pragma unroll
    for (int kk = 0; kk < 2; kk++)
      qb[mt][kk] = *(const short8*)&qt[nbase +
          (size_t)(qt0 + w * 32 + mt * 16 + il) * 64 + kk * 32 + q4 * 8];

  const short8 ones8 = { 0x3F80, 0x3F80, 0x3F80, 0x3F80,
                         0x3F80, 0x3F80, 0x3F80, 0x3F80 };  // bf16 1.0 x8

  f32x4 oaccT[2][4];                // [mt][ct]: O^T[c][t], c=ct*16+q4*4+r, t=mt*16+il
  f32x4 lacc[2];                    // denominator via ones-MFMA (all rows equal)
  #pragma unroll
  for (int mt = 0; mt < 2; mt++) {
    lacc[mt] = (f32x4){0.f, 0.f, 0.f, 0.f};
    #pragma unroll
    for (int ct = 0; ct < 4; ct++) oaccT[mt][ct] = (f32x4){0.f, 0.f, 0.f, 0.f};
  }

  // ---- prologue: tile 0 -> buf0; tile 1 -> regs ----
  short8 kreg0 = *(const short8*)&kt[nbase + (size_t)srow0 * 64 + scol];
  short8 kreg1 = *(const short8*)&kt[nbase + (size_t)srow1 * 64 + scol];
  short8 vreg0 = *(const short8*)&v[nbase + (size_t)srow0 * TT + scol];
  short8 vreg1 = *(const short8*)&v[nbase + (size_t)srow1 * TT + scol];
  *(short8*)&stage[srow0 * 72 + scol]        = kreg0;
  *(short8*)&stage[srow1 * 72 + scol]        = kreg1;
  *(short8*)&stage[4608 + srow0 * 72 + scol] = vreg0;
  *(short8*)&stage[4608 + srow1 * 72 + scol] = vreg1;
  kreg0 = *(const short8*)&kt[nbase + (size_t)(64 + srow0) * 64 + scol];
  kreg1 = *(const short8*)&kt[nbase + (size_t)(64 + srow1) * 64 + scol];
  vreg0 = *(const short8*)&v[nbase + (size_t)srow0 * TT + 64 + scol];
  vreg1 = *(const short8*)&v[nbase + (size_t)srow1 * TT + 64 + scol];
  __syncthreads();                     // buf0 visible

  #pragma unroll 1
  for (int st = 0; st < 16; st++) {
    const int cur = st & 1;
    short* ksc = stage + cur * 9216;          // compute buffer
    short* vsc = ksc + 4608;
    short* ksn = stage + (cur ^ 1) * 9216;    // fill buffer (tile st+1)
    short* vsn = ksn + 4608;

    if (st < 15) {                     // write tile st+1 (no conflict with ksc reads)
      *(short8*)&ksn[srow0 * 72 + scol] = kreg0;
      *(short8*)&ksn[srow1 * 72 + scol] = kreg1;
      *(short8*)&vsn[srow0 * 72 + scol] = vreg0;
      *(short8*)&vsn[srow1 * 72 + scol] = vreg1;
    }
    if (st < 14) {                     // prefetch tile st+2: in flight across compute
      const int s2 = (st + 2) * 64;
      kreg0 = *(const short8*)&kt[nbase + (size_t)(s2 + srow0) * 64 + scol];
      kreg1 = *(const short8*)&kt[nbase + (size_t)(s2 + srow1) * 64 + scol];
      vreg0 = *(const short8*)&v[nbase + (size_t)srow0 * TT + s2 + scol];
      vreg1 = *(const short8*)&v[nbase + (size_t)srow1 * TT + s2 + scol];
    }

    // ---- phase 1: S^T + exp -> P packed directly into K=32 B-frag halves.
    // pq[mt][u] word (st2&1)*2+p holds bf16 pair (P[s=q4*4+2p..+1][t]) of
    // strip st2 = 2u+(st2&1): k=q4*8+j maps to s=(j>>2)*16+q4*4+(j&3).
    uint4v pq[2][2];
    #pragma unroll
    for (int st2 = 0; st2 < 4; st2++) {
      short8 ka0 = *(const short8*)&ksc[(st2 * 16 + il) * 72 + q4 * 8];
      short8 ka1 = *(const short8*)&ksc[(st2 * 16 + il) * 72 + 32 + q4 * 8];
      #pragma unroll
      for (int mt = 0; mt < 2; mt++) {
        f32x4 sT = (f32x4){0.f, 0.f, 0.f, 0.f};
        sT = mfma32(ka0, qb[mt][0], sT);
        sT = mfma32(ka1, qb[mt][1], sT);
        float p0 = EXP2(sT[0]), p1 = EXP2(sT[1]), p2 = EXP2(sT[2]), p3 = EXP2(sT[3]);
        pq[mt][st2 >> 1][(st2 & 1) * 2]     = packbf2(rnd_u(p1), rnd_u(p0));
        pq[mt][st2 >> 1][(st2 & 1) * 2 + 1] = packbf2(rnd_u(p3), rnd_u(p2));
      }
    }
    short8 pb[2][2];                  // [mt][u]: K=32 B-frag for strip pair u
    #pragma unroll
    for (int mt = 0; mt < 2; mt++)
      #pragma unroll
      for (int u = 0; u < 2; u++) {
        pb[mt][u] = __builtin_bit_cast(short8, pq[mt][u]);
        lacc[mt] = mfma32(ones8, pb[mt][u], lacc[mt]);   // row-sum, K=32
      }

    // ---- phase 2: PV at K=32; permuted vs: h0/h1 ARE the strip-pair A-frags
    #pragma unroll
    for (int ct = 0; ct < 4; ct++) {
      short8 h0 = *(const short8*)&vsc[(ct * 16 + il) * 72 + q4 * 16];
      short8 h1 = *(const short8*)&vsc[(ct * 16 + il) * 72 + q4 * 16 + 8];
      #pragma unroll
      for (int mt = 0; mt < 2; mt++) {
        oaccT[mt][ct] = mfma32(h0, pb[mt][0], oaccT[mt][ct]);
        oaccT[mt][ct] = mfma32(h1, pb[mt][1], oaccT[mt][ct]);
      }
    }

    __syncthreads();   // tile st+1 visible; all reads of buf[cur] complete
  }

  // ================= epilogue ==============================================
  // loop-end barrier guarantees every wave's staging reads are done -> safe
  // to overwrite stage (obuf aliases it).
  float linv[2];
  #pragma unroll
  for (int mt = 0; mt < 2; mt++) linv[mt] = 1.f / lacc[mt][0];

  // O^T regs -> bf16 K=32 B-frags: concat of ct-pair (2u, 2u+1)
  uint4v obq[2][2];
  #pragma unroll
  for (int mt = 0; mt < 2; mt++)
    #pragma unroll
    for (int ct = 0; ct < 4; ct++) {
      float a = oaccT[mt][ct][0] * linv[mt], b = oaccT[mt][ct][1] * linv[mt];
      float c = oaccT[mt][ct][2] * linv[mt], d = oaccT[mt][ct][3] * linv[mt];
      obq[mt][ct >> 1][(ct & 1) * 2]     = packbf2(rnd_u(b), rnd_u(a));
      obq[mt][ct >> 1][(ct & 1) * 2 + 1] = packbf2(rnd_u(d), rnd_u(c));
    }
  short8 ob8[2][2];
  #pragma unroll
  for (int mt = 0; mt < 2; mt++)
    #pragma unroll
    for (int u = 0; u < 2; u++)
      ob8[mt][u] = __builtin_bit_cast(short8, obq[mt][u]);

  // res[o][t] = Wo(A) x O(B) at K=32 -> obuf[o][t_local] (fp32, stride 132)
  // wob is pre-permuted: one short8 = full K=32 A-frag per c-pair u.
  #pragma unroll
  for (int ot = 0; ot < 4; ot++) {
    short8 wa0 = *(const short8*)&wob[(ot * 16 + il) * 64 + q4 * 8];
    short8 wa1 = *(const short8*)&wob[(ot * 16 + il) * 64 + 32 + q4 * 8];
    #pragma unroll
    for (int mt = 0; mt < 2; mt++) {
      f32x4 res = (f32x4){0.f, 0.f, 0.f, 0.f};
      res = mfma32(wa0, ob8[mt][0], res);
      res = mfma32(wa1, ob8[mt][1], res);
      #pragma unroll
      for (int r = 0; r < 4; r++)
        obuf[(ot * 16 + q4 * 4 + r) * 132 + w * 32 + mt * 16 + il] = res[r];
    }
  }
  __syncthreads();

  // coalesced store + residual: full 128B lines (8-lane groups x float4)
  const int orow = tid >> 3;          // 0..31
  const int ocb  = (tid & 7) * 4;     // col base
  #pragma unroll
  for (int half = 0; half < 2; half++) {
    const int row = orow + half * 32;
    #pragma unroll
    for (int k = 0; k < 4; k++) {
      const int col = ocb + k * 32;
      float4 val = *(const float4*)&obuf[row * 132 + col];
      const size_t idx = nbase + (size_t)row * TT + qt0 + col;
      float4 xv = *(const float4*)&x[idx];
      val.x += xv.x; val.y += xv.y; val.z += xv.z; val.w += xv.w;
      *(float4*)&out[idx] = val;
    }
  }
}

// ---------------------------------------------------------------------------
extern "C" void kernel_launch(void* const* d_in, const int* in_sizes, int n_in,
                              void* d_out, int out_size, void* d_ws, size_t ws_size,
                              hipStream_t stream) {
  const float* x     = (const float*)d_in[0];
  const float* Wq    = (const float*)d_in[1];
  const float* Wk    = (const float*)d_in[2];
  const float* Wv    = (const float*)d_in[3];
  const float* Wo    = (const float*)d_in[4];
  const float* scale = (const float*)d_in[5];
  float* out = (float*)d_out;

  const size_t elems = (size_t)NB * CC * TT;
  bf16* wb  = (bf16*)d_ws;          // 16384 bf16 weights
  bf16* qtb = wb + 16384;
  bf16* ktb = qtb + elems;
  bf16* vv  = ktb + elems;

  wcvt<<<64, 256, 0, stream>>>(Wq, Wk, Wv, Wo, scale, wb);
  qkv_mfma<<<dim3(TT / 64, NB), 256, 0, stream>>>(x, wb, qtb, ktb, vv);
  attn_flash<<<dim3(NB * (TT / 128)), 256, 0, stream>>>(qtb, ktb, vv, wb + 12288, x, out);
}

// Round 5
// 140.029 us; speedup vs baseline: 1.1824x; 1.1204x over previous
//
#include <hip/hip_runtime.h>
#include <hip/hip_bf16.h>

typedef __hip_bfloat16 bf16;
typedef __attribute__((ext_vector_type(8))) short short8;   // 8 bf16 = K=32 MFMA A/B frag
typedef __attribute__((ext_vector_type(4))) short short4v;  // 4 bf16
typedef __attribute__((ext_vector_type(4))) float f32x4;    // MFMA C/D frag
typedef __attribute__((ext_vector_type(4))) unsigned uint4v;

#define NB 128   // B*TO
#define CC 64    // channels
#define TT 1024  // time

#if __has_builtin(__builtin_amdgcn_exp2f)
#define EXP2(x) __builtin_amdgcn_exp2f(x)
#else
#define EXP2(x) exp2f(x)
#endif

// ---- cheap bf16 conversion: round-half-up via +0x8000, pack 2 per v_perm ---
__device__ __forceinline__ unsigned rnd_u(float f) {
  return __builtin_bit_cast(unsigned, f) + 0x8000u;
}
__device__ __forceinline__ unsigned packbf2(unsigned uhi, unsigned ulo) {
  return __builtin_amdgcn_perm(uhi, ulo, 0x07060302);
}
__device__ __forceinline__ short4v pack4(float a, float b, float c, float d) {
  unsigned pd[2] = { packbf2(rnd_u(b), rnd_u(a)), packbf2(rnd_u(d), rnd_u(c)) };
  return *(const short4v*)pd;
}

__device__ __forceinline__ f32x4 mfma32(short8 a, short8 b, f32x4 c) {
  return __builtin_amdgcn_mfma_f32_16x16x32_bf16(a, b, c, 0, 0, 0);
}

// ---------------------------------------------------------------------------
// Kernel 0 (r16): weight-product precompute.
//   M[a][b]  = (sum_c Wk[c][a]*Wq[c][b]) * scale * log2(e)   (row-major, 64x64)
//   W2perm   = Wo*Wv stored in the attn-epilogue PERMUTED layout:
//              position o*64+u*32+q4*8+j holds W2[o][(2u+(j>>2))*16+q4*4+(j&3)],
//              W2[o][a] = sum_c Wo[o][c]*Wv[c][a].
// Algebra: S^T = x_s^T (Wk^T Wq) x_q ; out = (Wo Wv)(x_s P)/l + x_q.
// This deletes the q/k/v projection kernel and its 50 MB HBM round-trip.
// ---------------------------------------------------------------------------
__global__ __launch_bounds__(256) void wprep(
    const float* __restrict__ Wq, const float* __restrict__ Wk,
    const float* __restrict__ Wv, const float* __restrict__ Wo,
    const float* __restrict__ scale_p, bf16* __restrict__ wmw)
{
  const int g = blockIdx.x * 256 + threadIdx.x;
  float acc = 0.f;
  if (g < 4096) {
    const int a = g >> 6, b = g & 63;
    #pragma unroll 8
    for (int c = 0; c < 64; c++) acc += Wk[c * 64 + a] * Wq[c * 64 + b];
    acc *= (*scale_p) * 1.44269504089f;
    wmw[g] = __float2bfloat16(acc);
  } else {
    const int ii = g - 4096;
    const int o = ii >> 6, cp = ii & 63;          // cp = permuted position
    const int u = cp >> 5, q4 = (cp >> 3) & 3, j = cp & 7;
    const int a = (2 * u + (j >> 2)) * 16 + q4 * 4 + (j & 3);
    #pragma unroll 8
    for (int c = 0; c < 64; c++) acc += Wo[o * 64 + c] * Wv[c * 64 + a];
    wmw[g] = __float2bfloat16(acc);
  }
}

// ---------------------------------------------------------------------------
// Kernel 1 (r16): FULLY FUSED attention from raw x. r13's proven loop
// geometry (32 t/wave, grid 1024, 2 barriers/iter, 4 blocks/CU, LDS 33.8 KB)
// — r14 (fewer blocks) and r15 (dbuf) both regressed, so that structure is
// kept verbatim. Differences vs r13:
//  * PROLOGUE: stage x_q^T (128t x 64c bf16) via the qkv xs-pattern, compute
//    Y = M x_q with 16 MFMAs, round-trip D[a][t] -> LDS [t][a] (short4v,
//    contiguous in reg index) -> read Y B-frags yb (replaces the qt load).
//  * PER-ITER STAGING: read the fp32 x s-tile (4 float4/thread, same pattern
//    as qkv's xs stage) and write BOTH consumer layouts from the same regs:
//      ks[s][c]   (K-side A-frags; rows s, c contiguous)
//      vs[c][s']  (Z-side A-frags; s=a*16+b*4+j -> s'=b*16+a*4+j, which is
//                  CONTIGUOUS in e for a thread's 4 s-values)
//    Phase-1/phase-2/lacc consume them EXACTLY as r13 (verified layouts).
//  * EPILOGUE: res = W2perm x Z/l + x — identical code, wob -> w2.
// Layouts (m89/m120-verified): A[m=lane&15][k=quad*8+j];
// B[k=quad*8+j][n=lane&15]; C/D row=quad*4+reg, col=lane&15.
// ---------------------------------------------------------------------------
__global__ __launch_bounds__(256, 4) void attn_fused(
    const bf16* __restrict__ wm, const bf16* __restrict__ w2,
    const float* __restrict__ x, float* __restrict__ out)
{
  __shared__ float obuf[64 * 132];          // 33792 B; staging aliases front
  short* xq = (short*)obuf;                 // prologue [128 t][72]   (18432 B)
  short* ks = (short*)obuf;                 // loop: K-side [s][c]    (9216 B)
  short* vs = ks + 64 * 72;                 // loop: Z-side [c][s']   (9216 B)

  const int bid = blockIdx.x;
  const int n   = bid & 127;        // bid%8 == n%8 -> same-n blocks share an XCD
  const int qt0 = (bid >> 7) * 128;
  const int tid = threadIdx.x;
  const int w   = tid >> 6;
  const int il  = tid & 15;
  const int q4  = (tid & 63) >> 4;
  const size_t nbase = (size_t)n * (CC * TT);

  // staging thread coords (qkv xs pattern): 16 s-groups x 16 c-groups
  const int tc = tid & 15;          // 4 s (or t) columns: tc*4+e
  const int c0 = (tid >> 4) * 4;    // 4 c rows: c0+j

  // ================= prologue: Y = M x_q ===================================
  #pragma unroll
  for (int half = 0; half < 2; half++) {
    float fe[4][4];
    #pragma unroll
    for (int j = 0; j < 4; j++) {
      float4 fj = *(const float4*)&x[nbase + (size_t)(c0 + j) * TT + qt0 + half * 64 + tc * 4];
      fe[j][0] = fj.x; fe[j][1] = fj.y; fe[j][2] = fj.z; fe[j][3] = fj.w;
    }
    #pragma unroll
    for (int e = 0; e < 4; e++)
      *(short4v*)&xq[(half * 64 + tc * 4 + e) * 72 + c0] =
          pack4(fe[0][e], fe[1][e], fe[2][e], fe[3][e]);
  }
  __syncthreads();

  // Y-mfma: D[a][t] for this wave's 32 t-cols (t = w*32 + mt*16 + il)
  f32x4 yacc[4][2];
  #pragma unroll
  for (int at = 0; at < 4; at++)
    #pragma unroll
    for (int mt = 0; mt < 2; mt++) yacc[at][mt] = (f32x4){0.f, 0.f, 0.f, 0.f};
  #pragma unroll
  for (int kk = 0; kk < 2; kk++) {
    short8 xb0 = *(const short8*)&xq[(w * 32 + il) * 72 + kk * 32 + q4 * 8];
    short8 xb1 = *(const short8*)&xq[(w * 32 + 16 + il) * 72 + kk * 32 + q4 * 8];
    #pragma unroll
    for (int at = 0; at < 4; at++) {
      short8 ma = *(const short8*)&wm[(at * 16 + il) * 64 + kk * 32 + q4 * 8];
      yacc[at][0] = mfma32(ma, xb0, yacc[at][0]);
      yacc[at][1] = mfma32(ma, xb1, yacc[at][1]);
    }
  }
  __syncthreads();          // all xq reads done before overwrite
  // D[a = at*16+q4*4+r][t] -> LDS [t][a]; contiguous in r -> short4v
  #pragma unroll
  for (int at = 0; at < 4; at++)
    #pragma unroll
    for (int mt = 0; mt < 2; mt++)
      *(short4v*)&xq[(w * 32 + mt * 16 + il) * 72 + at * 16 + q4 * 4] =
          pack4(yacc[at][mt][0], yacc[at][mt][1], yacc[at][mt][2], yacc[at][mt][3]);
  __syncthreads();
  // Y B-frags (replace r13's qt load): B[k=a][n=t]
  short8 yb[2][2];
  #pragma unroll
  for (int mt = 0; mt < 2; mt++)
    #pragma unroll
    for (int kk = 0; kk < 2; kk++)
      yb[mt][kk] = *(const short8*)&xq[(w * 32 + mt * 16 + il) * 72 + kk * 32 + q4 * 8];

  const short8 ones8 = { 0x3F80, 0x3F80, 0x3F80, 0x3F80,
                         0x3F80, 0x3F80, 0x3F80, 0x3F80 };  // bf16 1.0 x8

  f32x4 oaccT[2][4];                // [mt][ct]: Z[a][t], a=ct*16+q4*4+r, t=mt*16+il
  f32x4 lacc[2];                    // denominator via ones-MFMA
  #pragma unroll
  for (int mt = 0; mt < 2; mt++) {
    lacc[mt] = (f32x4){0.f, 0.f, 0.f, 0.f};
    #pragma unroll
    for (int ct = 0; ct < 4; ct++) oaccT[mt][ct] = (f32x4){0.f, 0.f, 0.f, 0.f};
  }

  // prefetch s-tile 0 (fp32)
  float fe[4][4];
  #pragma unroll
  for (int j = 0; j < 4; j++) {
    float4 fj = *(const float4*)&x[nbase + (size_t)(c0 + j) * TT + tc * 4];
    fe[j][0] = fj.x; fe[j][1] = fj.y; fe[j][2] = fj.z; fe[j][3] = fj.w;
  }

  #pragma unroll 1
  for (int st = 0; st < 16; st++) {
    __syncthreads();                 // prev-iter compute reads done (iter 0: yb reads)
    // K-side [s][c]: c contiguous
    #pragma unroll
    for (int e = 0; e < 4; e++)
      *(short4v*)&ks[(tc * 4 + e) * 72 + c0] = pack4(fe[0][e], fe[1][e], fe[2][e], fe[3][e]);
    // Z-side [c][s']: s = tc*4+e -> s' = (tc&3)*16 + (tc>>2)*4 + e (contig in e)
    #pragma unroll
    for (int j = 0; j < 4; j++)
      *(short4v*)&vs[(c0 + j) * 72 + (tc & 3) * 16 + (tc >> 2) * 4] =
          pack4(fe[j][0], fe[j][1], fe[j][2], fe[j][3]);
    if (st < 15) {                   // prefetch st+1: in flight across barrier
      const int s1 = (st + 1) * 64;
      #pragma unroll
      for (int j = 0; j < 4; j++) {
        float4 fj = *(const float4*)&x[nbase + (size_t)(c0 + j) * TT + s1 + tc * 4];
        fe[j][0] = fj.x; fe[j][1] = fj.y; fe[j][2] = fj.z; fe[j][3] = fj.w;
      }
    }
    __syncthreads();                 // ks/vs visible

    // ---- phase 1: S^T = x_s^T Y, exp2 -> P packed into K=32 B-frag halves
    uint4v pq[2][2];
    #pragma unroll
    for (int st2 = 0; st2 < 4; st2++) {
      short8 ka0 = *(const short8*)&ks[(st2 * 16 + il) * 72 + q4 * 8];
      short8 ka1 = *(const short8*)&ks[(st2 * 16 + il) * 72 + 32 + q4 * 8];
      #pragma unroll
      for (int mt = 0; mt < 2; mt++) {
        f32x4 sT = (f32x4){0.f, 0.f, 0.f, 0.f};
        sT = mfma32(ka0, yb[mt][0], sT);
        sT = mfma32(ka1, yb[mt][1], sT);
        float p0 = EXP2(sT[0]), p1 = EXP2(sT[1]), p2 = EXP2(sT[2]), p3 = EXP2(sT[3]);
        pq[mt][st2 >> 1][(st2 & 1) * 2]     = packbf2(rnd_u(p1), rnd_u(p0));
        pq[mt][st2 >> 1][(st2 & 1) * 2 + 1] = packbf2(rnd_u(p3), rnd_u(p2));
      }
    }
    short8 pb[2][2];
    #pragma unroll
    for (int mt = 0; mt < 2; mt++)
      #pragma unroll
      for (int u = 0; u < 2; u++) {
        pb[mt][u] = __builtin_bit_cast(short8, pq[mt][u]);
        lacc[mt] = mfma32(ones8, pb[mt][u], lacc[mt]);   // row-sum, K=32
      }

    // ---- phase 2: Z += x_s P at K=32; permuted vs: h0/h1 are strip-pair A-frags
    #pragma unroll
    for (int ct = 0; ct < 4; ct++) {
      short8 h0 = *(const short8*)&vs[(ct * 16 + il) * 72 + q4 * 16];
      short8 h1 = *(const short8*)&vs[(ct * 16 + il) * 72 + q4 * 16 + 8];
      #pragma unroll
      for (int mt = 0; mt < 2; mt++) {
        oaccT[mt][ct] = mfma32(h0, pb[mt][0], oaccT[mt][ct]);
        oaccT[mt][ct] = mfma32(h1, pb[mt][1], oaccT[mt][ct]);
      }
    }
  }

  // ================= epilogue ==============================================
  float linv[2];
  #pragma unroll
  for (int mt = 0; mt < 2; mt++) linv[mt] = 1.f / lacc[mt][0];

  // Z regs -> bf16 K=32 B-frags: concat of ct-pair (2u, 2u+1)
  uint4v obq[2][2];
  #pragma unroll
  for (int mt = 0; mt < 2; mt++)
    #pragma unroll
    for (int ct = 0; ct < 4; ct++) {
      float a = oaccT[mt][ct][0] * linv[mt], b = oaccT[mt][ct][1] * linv[mt];
      float c = oaccT[mt][ct][2] * linv[mt], d = oaccT[mt][ct][3] * linv[mt];
      obq[mt][ct >> 1][(ct & 1) * 2]     = packbf2(rnd_u(b), rnd_u(a));
      obq[mt][ct >> 1][(ct & 1) * 2 + 1] = packbf2(rnd_u(d), rnd_u(c));
    }
  short8 ob8[2][2];
  #pragma unroll
  for (int mt = 0; mt < 2; mt++)
    #pragma unroll
    for (int u = 0; u < 2; u++)
      ob8[mt][u] = __builtin_bit_cast(short8, obq[mt][u]);

  __syncthreads();   // all loop reads of ks/vs done before obuf overwrites them

  // res[o][t] = W2(A) x Z(B) at K=32 -> obuf[o][t_local] (fp32, stride 132)
  #pragma unroll
  for (int ot = 0; ot < 4; ot++) {
    short8 wa0 = *(const short8*)&w2[(ot * 16 + il) * 64 + q4 * 8];
    short8 wa1 = *(const short8*)&w2[(ot * 16 + il) * 64 + 32 + q4 * 8];
    #pragma unroll
    for (int mt = 0; mt < 2; mt++) {
      f32x4 res = (f32x4){0.f, 0.f, 0.f, 0.f};
      res = mfma32(wa0, ob8[mt][0], res);
      res = mfma32(wa1, ob8[mt][1], res);
      #pragma unroll
      for (int r = 0; r < 4; r++)
        obuf[(ot * 16 + q4 * 4 + r) * 132 + w * 32 + mt * 16 + il] = res[r];
    }
  }
  __syncthreads();

  // coalesced store + residual: full 128B lines (8-lane groups x float4)
  const int orow = tid >> 3;          // 0..31
  const int ocb  = (tid & 7) * 4;     // col base
  #pragma unroll
  for (int half = 0; half < 2; half++) {
    const int row = orow + half * 32;
    #pragma unroll
    for (int k = 0; k < 4; k++) {
      const int col = ocb + k * 32;
      float4 val = *(const float4*)&obuf[row * 132 + col];
      const size_t idx = nbase + (size_t)row * TT + qt0 + col;
      float4 xv = *(const float4*)&x[idx];
      val.x += xv.x; val.y += xv.y; val.z += xv.z; val.w += xv.w;
      *(float4*)&out[idx] = val;
    }
  }
}

// ---------------------------------------------------------------------------
extern "C" void kernel_launch(void* const* d_in, const int* in_sizes, int n_in,
                              void* d_out, int out_size, void* d_ws, size_t ws_size,
                              hipStream_t stream) {
  const float* x     = (const float*)d_in[0];
  const float* Wq    = (const float*)d_in[1];
  const float* Wk    = (const float*)d_in[2];
  const float* Wv    = (const float*)d_in[3];
  const float* Wo    = (const float*)d_in[4];
  const float* scale = (const float*)d_in[5];
  float* out = (float*)d_out;

  bf16* wmw = (bf16*)d_ws;          // [0..4095] = M, [4096..8191] = W2 (permuted)

  wprep<<<32, 256, 0, stream>>>(Wq, Wk, Wv, Wo, scale, wmw);
  attn_fused<<<1024, 256, 0, stream>>>(wmw, wmw + 4096, x, out);
}

// Round 6
// 135.705 us; speedup vs baseline: 1.2201x; 1.0319x over previous
//
#include <hip/hip_runtime.h>
#include <hip/hip_bf16.h>

typedef __hip_bfloat16 bf16;
typedef __attribute__((ext_vector_type(8))) short short8;   // 8 bf16 = K=32 MFMA A/B frag
typedef __attribute__((ext_vector_type(4))) short short4v;  // 4 bf16
typedef __attribute__((ext_vector_type(4))) float f32x4;    // MFMA C/D frag
typedef __attribute__((ext_vector_type(4))) unsigned uint4v;

#define NB 128   // B*TO
#define CC 64    // channels
#define TT 1024  // time

#if __has_builtin(__builtin_amdgcn_exp2f)
#define EXP2(x) __builtin_amdgcn_exp2f(x)
#else
#define EXP2(x) exp2f(x)
#endif

// ---- cheap bf16 conversion: round-half-up via +0x8000, pack 2 per v_perm ---
__device__ __forceinline__ unsigned rnd_u(float f) {
  return __builtin_bit_cast(unsigned, f) + 0x8000u;
}
__device__ __forceinline__ unsigned packbf2(unsigned uhi, unsigned ulo) {
  return __builtin_amdgcn_perm(uhi, ulo, 0x07060302);
}
__device__ __forceinline__ short4v pack4(float a, float b, float c, float d) {
  unsigned pd[2] = { packbf2(rnd_u(b), rnd_u(a)), packbf2(rnd_u(d), rnd_u(c)) };
  return *(const short4v*)pd;
}

__device__ __forceinline__ f32x4 mfma32(short8 a, short8 b, f32x4 c) {
  return __builtin_amdgcn_mfma_f32_16x16x32_bf16(a, b, c, 0, 0, 0);
}

// ---------------------------------------------------------------------------
// Kernel 0: weight-product precompute (r16).
//   M[a][b]  = (sum_c Wk[c][a]*Wq[c][b]) * scale * log2(e)   (row-major, 64x64)
//   W2perm   = Wo*Wv stored in the attn-epilogue PERMUTED layout:
//              position o*64+u*32+q4*8+j holds W2[o][(2u+(j>>2))*16+q4*4+(j&3)],
//              W2[o][a] = sum_c Wo[o][c]*Wv[c][a].
// Algebra: S^T = x_s^T (Wk^T Wq) x_q ; out = (Wo Wv)(x_s P)/l + x_q.
// ---------------------------------------------------------------------------
__global__ __launch_bounds__(256) void wprep(
    const float* __restrict__ Wq, const float* __restrict__ Wk,
    const float* __restrict__ Wv, const float* __restrict__ Wo,
    const float* __restrict__ scale_p, bf16* __restrict__ wmw)
{
  const int g = blockIdx.x * 256 + threadIdx.x;
  float acc = 0.f;
  if (g < 4096) {
    const int a = g >> 6, b = g & 63;
    #pragma unroll 8
    for (int c = 0; c < 64; c++) acc += Wk[c * 64 + a] * Wq[c * 64 + b];
    acc *= (*scale_p) * 1.44269504089f;
    wmw[g] = __float2bfloat16(acc);
  } else {
    const int ii = g - 4096;
    const int o = ii >> 6, cp = ii & 63;          // cp = permuted position
    const int u = cp >> 5, q4 = (cp >> 3) & 3, j = cp & 7;
    const int a = (2 * u + (j >> 2)) * 16 + q4 * 4 + (j & 3);
    #pragma unroll 8
    for (int c = 0; c < 64; c++) acc += Wo[o * 64 + c] * Wv[c * 64 + a];
    wmw[g] = __float2bfloat16(acc);
  }
}

// ---------------------------------------------------------------------------
// Kernel 1: FULLY FUSED attention from raw x (r16 structure).
// r17 change: CONFLICT-FREE staging. r16's staging (4c x 4s per thread,
// 8B writes at (tc*4+e)*72+c0) hit 8-way bank conflicts (bank = 16(tc&1)+
// 2(lane>>4), 8 banks/64 lanes) -> SQ_LDS_BANK_CONFLICT 12.98M and +17us.
// New mapping: each thread covers 8 c-rows x 2 s-cols (cg=tid>>5, ts=tid&31):
//  * global read: 8x float2 (8B/lane, 256B segments, coalesced)
//  * ks[s][c]  write: 2x b128 at (2ts+e)*72 + cg*8 -> start banks
//    8(lane&3)+4(lane>>5): 8 disjoint 4-bank groups x 8 lanes = minimum
//    cycles (conflict-free).
//  * vs[c][s'] write: 8x b32 at (cg*8+j)*72 + sp0, sp0=((ts>>1)&3)*16+
//    (ts>>3)*4+2(ts&1): 32 distinct banks, 2 lanes each = free.
// Layout CONTENTS identical to r16; all reads (phase1/2, yb, epilogue)
// unchanged. Same remap for the prologue xq stage.
// Layouts (m89/m120-verified): A[m=lane&15][k=quad*8+j];
// B[k=quad*8+j][n=lane&15]; C/D row=quad*4+reg, col=lane&15.
// ---------------------------------------------------------------------------
__global__ __launch_bounds__(256, 4) void attn_fused(
    const bf16* __restrict__ wm, const bf16* __restrict__ w2,
    const float* __restrict__ x, float* __restrict__ out)
{
  __shared__ float obuf[64 * 132];          // 33792 B; staging aliases front
  short* xq = (short*)obuf;                 // prologue [128 t][72]   (18432 B)
  short* ks = (short*)obuf;                 // loop: K-side [s][c]    (9216 B)
  short* vs = ks + 64 * 72;                 // loop: Z-side [c][s']   (9216 B)

  const int bid = blockIdx.x;
  const int n   = bid & 127;        // bid%8 == n%8 -> same-n blocks share an XCD
  const int qt0 = (bid >> 7) * 128;
  const int tid = threadIdx.x;
  const int w   = tid >> 6;
  const int il  = tid & 15;
  const int q4  = (tid & 63) >> 4;
  const size_t nbase = (size_t)n * (CC * TT);

  // staging thread coords (r17): 8 c-rows x 2 s-cols per thread
  const int ts  = tid & 31;         // s-pair index: s = ts*2 + e
  const int cg  = tid >> 5;         // c-group: c = cg*8 + j
  const int krow = ts * 2;
  const int sp0 = ((ts >> 1) & 3) * 16 + (ts >> 3) * 4 + (ts & 1) * 2;  // perm'd s

  // ================= prologue: Y = M x_q ===================================
  #pragma unroll
  for (int half = 0; half < 2; half++) {
    float2 xr[8];
    #pragma unroll
    for (int j = 0; j < 8; j++)
      xr[j] = *(const float2*)&x[nbase + (size_t)(cg * 8 + j) * TT + qt0 + half * 64 + ts * 2];
    #pragma unroll
    for (int e = 0; e < 2; e++) {
      unsigned kd[4];
      #pragma unroll
      for (int d = 0; d < 4; d++) {
        float lo = e ? xr[2 * d].y     : xr[2 * d].x;
        float hi = e ? xr[2 * d + 1].y : xr[2 * d + 1].x;
        kd[d] = packbf2(rnd_u(hi), rnd_u(lo));
      }
      *(uint4v*)&xq[(half * 64 + krow + e) * 72 + cg * 8] = *(const uint4v*)kd;
    }
  }
  __syncthreads();

  // Y-mfma: D[a][t] for this wave's 32 t-cols (t = w*32 + mt*16 + il)
  f32x4 yacc[4][2];
  #pragma unroll
  for (int at = 0; at < 4; at++)
    #pragma unroll
    for (int mt = 0; mt < 2; mt++) yacc[at][mt] = (f32x4){0.f, 0.f, 0.f, 0.f};
  #pragma unroll
  for (int kk = 0; kk < 2; kk++) {
    short8 xb0 = *(const short8*)&xq[(w * 32 + il) * 72 + kk * 32 + q4 * 8];
    short8 xb1 = *(const short8*)&xq[(w * 32 + 16 + il) * 72 + kk * 32 + q4 * 8];
    #pragma unroll
    for (int at = 0; at < 4; at++) {
      short8 ma = *(const short8*)&wm[(at * 16 + il) * 64 + kk * 32 + q4 * 8];
      yacc[at][0] = mfma32(ma, xb0, yacc[at][0]);
      yacc[at][1] = mfma32(ma, xb1, yacc[at][1]);
    }
  }
  __syncthreads();          // all xq reads done before overwrite
  // D[a = at*16+q4*4+r][t] -> LDS [t][a]; contiguous in r -> short4v
  #pragma unroll
  for (int at = 0; at < 4; at++)
    #pragma unroll
    for (int mt = 0; mt < 2; mt++)
      *(short4v*)&xq[(w * 32 + mt * 16 + il) * 72 + at * 16 + q4 * 4] =
          pack4(yacc[at][mt][0], yacc[at][mt][1], yacc[at][mt][2], yacc[at][mt][3]);
  __syncthreads();
  // Y B-frags: B[k=a][n=t]
  short8 yb[2][2];
  #pragma unroll
  for (int mt = 0; mt < 2; mt++)
    #pragma unroll
    for (int kk = 0; kk < 2; kk++)
      yb[mt][kk] = *(const short8*)&xq[(w * 32 + mt * 16 + il) * 72 + kk * 32 + q4 * 8];

  const short8 ones8 = { 0x3F80, 0x3F80, 0x3F80, 0x3F80,
                         0x3F80, 0x3F80, 0x3F80, 0x3F80 };  // bf16 1.0 x8

  f32x4 oaccT[2][4];                // [mt][ct]: Z[a][t], a=ct*16+q4*4+r, t=mt*16+il
  f32x4 lacc[2];                    // denominator via ones-MFMA
  #pragma unroll
  for (int mt = 0; mt < 2; mt++) {
    lacc[mt] = (f32x4){0.f, 0.f, 0.f, 0.f};
    #pragma unroll
    for (int ct = 0; ct < 4; ct++) oaccT[mt][ct] = (f32x4){0.f, 0.f, 0.f, 0.f};
  }

  // prefetch s-tile 0 (fp32): 8 rows x 2 cols
  float2 xr[8];
  #pragma unroll
  for (int j = 0; j < 8; j++)
    xr[j] = *(const float2*)&x[nbase + (size_t)(cg * 8 + j) * TT + ts * 2];

  #pragma unroll 1
  for (int st = 0; st < 16; st++) {
    __syncthreads();                 // prev-iter compute reads done (iter 0: yb reads)
    // ks[s][c]: 2x b128, conflict-free start banks
    #pragma unroll
    for (int e = 0; e < 2; e++) {
      unsigned kd[4];
      #pragma unroll
      for (int d = 0; d < 4; d++) {
        float lo = e ? xr[2 * d].y     : xr[2 * d].x;
        float hi = e ? xr[2 * d + 1].y : xr[2 * d + 1].x;
        kd[d] = packbf2(rnd_u(hi), rnd_u(lo));
      }
      *(uint4v*)&ks[(krow + e) * 72 + cg * 8] = *(const uint4v*)kd;
    }
    // vs[c][s']: 8x b32, 2 lanes/bank (free)
    #pragma unroll
    for (int j = 0; j < 8; j++)
      *(unsigned*)&vs[(cg * 8 + j) * 72 + sp0] = packbf2(rnd_u(xr[j].y), rnd_u(xr[j].x));
    if (st < 15) {                   // prefetch st+1: in flight across barrier
      const int s1 = (st + 1) * 64;
      #pragma unroll
      for (int j = 0; j < 8; j++)
        xr[j] = *(const float2*)&x[nbase + (size_t)(cg * 8 + j) * TT + s1 + ts * 2];
    }
    __syncthreads();                 // ks/vs visible

    // ---- phase 1: S^T = x_s^T Y, exp2 -> P packed into K=32 B-frag halves
    uint4v pq[2][2];
    #pragma unroll
    for (int st2 = 0; st2 < 4; st2++) {
      short8 ka0 = *(const short8*)&ks[(st2 * 16 + il) * 72 + q4 * 8];
      short8 ka1 = *(const short8*)&ks[(st2 * 16 + il) * 72 + 32 + q4 * 8];
      #pragma unroll
      for (int mt = 0; mt < 2; mt++) {
        f32x4 sT = (f32x4){0.f, 0.f, 0.f, 0.f};
        sT = mfma32(ka0, yb[mt][0], sT);
        sT = mfma32(ka1, yb[mt][1], sT);
        float p0 = EXP2(sT[0]), p1 = EXP2(sT[1]), p2 = EXP2(sT[2]), p3 = EXP2(sT[3]);
        pq[mt][st2 >> 1][(st2 & 1) * 2]     = packbf2(rnd_u(p1), rnd_u(p0));
        pq[mt][st2 >> 1][(st2 & 1) * 2 + 1] = packbf2(rnd_u(p3), rnd_u(p2));
      }
    }
    short8 pb[2][2];
    #pragma unroll
    for (int mt = 0; mt < 2; mt++)
      #pragma unroll
      for (int u = 0; u < 2; u++) {
        pb[mt][u] = __builtin_bit_cast(short8, pq[mt][u]);
        lacc[mt] = mfma32(ones8, pb[mt][u], lacc[mt]);   // row-sum, K=32
      }

    // ---- phase 2: Z += x_s P at K=32; permuted vs: h0/h1 are strip-pair A-frags
    #pragma unroll
    for (int ct = 0; ct < 4; ct++) {
      short8 h0 = *(const short8*)&vs[(ct * 16 + il) * 72 + q4 * 16];
      short8 h1 = *(const short8*)&vs[(ct * 16 + il) * 72 + q4 * 16 + 8];
      #pragma unroll
      for (int mt = 0; mt < 2; mt++) {
        oaccT[mt][ct] = mfma32(h0, pb[mt][0], oaccT[mt][ct]);
        oaccT[mt][ct] = mfma32(h1, pb[mt][1], oaccT[mt][ct]);
      }
    }
  }

  // ================= epilogue ==============================================
  float linv[2];
  #pragma unroll
  for (int mt = 0; mt < 2; mt++) linv[mt] = 1.f / lacc[mt][0];

  // Z regs -> bf16 K=32 B-frags: concat of ct-pair (2u, 2u+1)
  uint4v obq[2][2];
  #pragma unroll
  for (int mt = 0; mt < 2; mt++)
    #pragma unroll
    for (int ct = 0; ct < 4; ct++) {
      float a = oaccT[mt][ct][0] * linv[mt], b = oaccT[mt][ct][1] * linv[mt];
      float c = oaccT[mt][ct][2] * linv[mt], d = oaccT[mt][ct][3] * linv[mt];
      obq[mt][ct >> 1][(ct & 1) * 2]     = packbf2(rnd_u(b), rnd_u(a));
      obq[mt][ct >> 1][(ct & 1) * 2 + 1] = packbf2(rnd_u(d), rnd_u(c));
    }
  short8 ob8[2][2];
  #pragma unroll
  for (int mt = 0; mt < 2; mt++)
    #pragma unroll
    for (int u = 0; u < 2; u++)
      ob8[mt][u] = __builtin_bit_cast(short8, obq[mt][u]);

  __syncthreads();   // all loop reads of ks/vs done before obuf overwrites them

  // res[o][t] = W2(A) x Z(B) at K=32 -> obuf[o][t_local] (fp32, stride 132)
  #pragma unroll
  for (int ot = 0; ot < 4; ot++) {
    short8 wa0 = *(const short8*)&w2[(ot * 16 + il) * 64 + q4 * 8];
    short8 wa1 = *(const short8*)&w2[(ot * 16 + il) * 64 + 32 + q4 * 8];
    #pragma unroll
    for (int mt = 0; mt < 2; mt++) {
      f32x4 res = (f32x4){0.f, 0.f, 0.f, 0.f};
      res = mfma32(wa0, ob8[mt][0], res);
      res = mfma32(wa1, ob8[mt][1], res);
      #pragma unroll
      for (int r = 0; r < 4; r++)
        obuf[(ot * 16 + q4 * 4 + r) * 132 + w * 32 + mt * 16 + il] = res[r];
    }
  }
  __syncthreads();

  // coalesced store + residual: full 128B lines (8-lane groups x float4)
  const int orow = tid >> 3;          // 0..31
  const int ocb  = (tid & 7) * 4;     // col base
  #pragma unroll
  for (int half = 0; half < 2; half++) {
    const int row = orow + half * 32;
    #pragma unroll
    for (int k = 0; k < 4; k++) {
      const int col = ocb + k * 32;
      float4 val = *(const float4*)&obuf[row * 132 + col];
      const size_t idx = nbase + (size_t)row * TT + qt0 + col;
      float4 xv = *(const float4*)&x[idx];
      val.x += xv.x; val.y += xv.y; val.z += xv.z; val.w += xv.w;
      *(float4*)&out[idx] = val;
    }
  }
}

// ---------------------------------------------------------------------------
extern "C" void kernel_launch(void* const* d_in, const int* in_sizes, int n_in,
                              void* d_out, int out_size, void* d_ws, size_t ws_size,
                              hipStream_t stream) {
  const float* x     = (const float*)d_in[0];
  const float* Wq    = (const float*)d_in[1];
  const float* Wk    = (const float*)d_in[2];
  const float* Wv    = (const float*)d_in[3];
  const float* Wo    = (const float*)d_in[4];
  const float* scale = (const float*)d_in[5];
  float* out = (float*)d_out;

  bf16* wmw = (bf16*)d_ws;          // [0..4095] = M, [4096..8191] = W2 (permuted)

  wprep<<<32, 256, 0, stream>>>(Wq, Wk, Wv, Wo, scale, wmw);
  attn_fused<<<1024, 256, 0, stream>>>(wmw, wmw + 4096, x, out);
}